// Round 4
// baseline (259.169 us; speedup 1.0000x reference)
//
#include <hip/hip_runtime.h>
#include <math.h>

// DirectionalContrastiveLoss — N=8, C=192, H=W=112, T=0.1
//
// R4: channel-split x4 (896 blocks = 3.5/CU vs R2's 224 = 0.875/CU, which was
// the real R2 limiter: barrier-coupled single block per CU). Each block keeps
// R2's LDS halo-tile double-buffer but computes only UNNORMALIZED dot partials
// for its 48-channel slice (norm == center dot -> no ssbuf, no extra barrier),
// written to d_ws. dcl_norm combines center dots into an inv-norm plane;
// dcl_loss combines dot partials + neighbor norms + masked softmax.
// LDS staged as float2 channel pairs -> ds_read_b64 halves LDS instr count.

namespace {
constexpr int N_ = 8, C_ = 192, H_ = 112, W_ = 112;
constexpr int HW = H_ * W_;
constexpr int NPIX = N_ * HW;              // 100352
constexpr int TH = 4;
constexpr int TROWS = TH + 2;              // 6
constexpr int TWID = W_ + 2;               // 114
constexpr int TILE_E = TROWS * TWID;       // 684
constexpr int NT = TH * W_;                // 448 threads = 7 waves
constexpr int EXTRA = TILE_E - NT;         // 236
constexpr int CSPLIT = 4;
constexpr int CPB = C_ / CSPLIT;           // 48 channels per block
constexpr int KCH = 4;                     // channels per chunk (2 float2 groups)
constexpr int NCHUNK = CPB / KCH;          // 12
constexpr float INV_T = 10.0f;
constexpr double TOTAL = (double)N_ * N_ * H_ * W_;  // 802816
constexpr int NT2 = 256;
constexpr int NBLK2 = NPIX / NT2;          // 392 (exact)
constexpr size_t PART_FLOATS = (size_t)CSPLIT * 9 * NPIX;
constexpr size_t WS_NEEDED = (PART_FLOATS + NPIX) * sizeof(float) + sizeof(double);
}

__device__ __forceinline__ float sel3(int d, float a, float b, float c) {
    float r = (d < 0) ? a : b;
    return (d > 0) ? c : r;
}

// ---------------------------------------------------------------- K1: partials
extern "C" __global__ void __launch_bounds__(NT)
dcl_part(const float* __restrict__ feat, float* __restrict__ part)
{
    __shared__ float2 tiles[2][2][TILE_E];   // [buf][pair-group][slot] = 21.9 KB

    const int tid   = threadIdx.x;
    const int gy0   = blockIdx.x * TH;
    const int n     = blockIdx.y;
    const int slice = blockIdx.z;

    int gofs0, gofs1 = 0;
    {
        int r = tid / TWID, col = tid - r * TWID;
        gofs0 = min(max(gy0 + r - 1, 0), H_ - 1) * W_ + min(max(col - 1, 0), W_ - 1);
        if (tid < EXTRA) {
            int t2 = tid + NT;
            r = t2 / TWID; col = t2 - r * TWID;
            gofs1 = min(max(gy0 + r - 1, 0), H_ - 1) * W_ + min(max(col - 1, 0), W_ - 1);
        }
    }
    const int ty = tid / W_, tx = tid - ty * W_;
    const int ci = (ty + 1) * TWID + (tx + 1);
    const float* __restrict__ plane =
        feat + ((size_t)n * C_ + (size_t)slice * CPB) * HW;

    float s[9];
    #pragma unroll
    for (int d = 0; d < 9; ++d) s[d] = 0.0f;

    // prologue: chunk 0 -> buffer 0
    {
        float v0 = plane[gofs0], v1 = plane[HW + gofs0];
        float v2 = plane[2 * HW + gofs0], v3 = plane[3 * HW + gofs0];
        tiles[0][0][tid] = make_float2(v0, v1);
        tiles[0][1][tid] = make_float2(v2, v3);
        if (tid < EXTRA) {
            float u0 = plane[gofs1], u1 = plane[HW + gofs1];
            float u2 = plane[2 * HW + gofs1], u3 = plane[3 * HW + gofs1];
            tiles[0][0][tid + NT] = make_float2(u0, u1);
            tiles[0][1][tid + NT] = make_float2(u2, u3);
        }
    }
    __syncthreads();

    for (int t = 0; t < NCHUNK; ++t) {
        float pv[KCH], qv[KCH];
        const bool more = (t + 1 < NCHUNK);
        if (more) {
            const float* p = plane + (size_t)(t + 1) * KCH * HW;
            #pragma unroll
            for (int k = 0; k < KCH; ++k) pv[k] = p[(size_t)k * HW + gofs0];
            if (tid < EXTRA) {
                #pragma unroll
                for (int k = 0; k < KCH; ++k) qv[k] = p[(size_t)k * HW + gofs1];
            }
        }

        #pragma unroll
        for (int g = 0; g < 2; ++g) {
            const float2* __restrict__ cp = tiles[t & 1][g];
            float2 fc  = cp[ci];
            float2 n00 = cp[ci - TWID - 1];
            float2 n01 = cp[ci - TWID];
            float2 n02 = cp[ci - TWID + 1];
            float2 n10 = cp[ci - 1];
            float2 n12 = cp[ci + 1];
            float2 n20 = cp[ci + TWID - 1];
            float2 n21 = cp[ci + TWID];
            float2 n22 = cp[ci + TWID + 1];
            s[0] = fmaf(fc.x, n00.x, s[0]); s[0] = fmaf(fc.y, n00.y, s[0]);
            s[1] = fmaf(fc.x, n01.x, s[1]); s[1] = fmaf(fc.y, n01.y, s[1]);
            s[2] = fmaf(fc.x, n02.x, s[2]); s[2] = fmaf(fc.y, n02.y, s[2]);
            s[3] = fmaf(fc.x, n10.x, s[3]); s[3] = fmaf(fc.y, n10.y, s[3]);
            s[4] = fmaf(fc.x, fc.x,  s[4]); s[4] = fmaf(fc.y, fc.y,  s[4]);
            s[5] = fmaf(fc.x, n12.x, s[5]); s[5] = fmaf(fc.y, n12.y, s[5]);
            s[6] = fmaf(fc.x, n20.x, s[6]); s[6] = fmaf(fc.y, n20.y, s[6]);
            s[7] = fmaf(fc.x, n21.x, s[7]); s[7] = fmaf(fc.y, n21.y, s[7]);
            s[8] = fmaf(fc.x, n22.x, s[8]); s[8] = fmaf(fc.y, n22.y, s[8]);
        }

        if (more) {
            float2* nxt0 = tiles[(t + 1) & 1][0];
            float2* nxt1 = tiles[(t + 1) & 1][1];
            nxt0[tid] = make_float2(pv[0], pv[1]);
            nxt1[tid] = make_float2(pv[2], pv[3]);
            if (tid < EXTRA) {
                nxt0[tid + NT] = make_float2(qv[0], qv[1]);
                nxt1[tid + NT] = make_float2(qv[2], qv[3]);
            }
        }
        __syncthreads();
    }

    const int gpix = n * HW + (gy0 + ty) * W_ + tx;
    const size_t po = (size_t)slice * 9 * NPIX;
    #pragma unroll
    for (int d = 0; d < 9; ++d)
        part[po + (size_t)d * NPIX + gpix] = s[d];
}

// ---------------------------------------------------------------- K2a: norms
extern "C" __global__ void __launch_bounds__(NT2)
dcl_norm(const float* __restrict__ part, float* __restrict__ inv)
{
    const int g = blockIdx.x * NT2 + threadIdx.x;
    float ss = 0.0f;
    #pragma unroll
    for (int sl = 0; sl < CSPLIT; ++sl)
        ss += part[((size_t)sl * 9 + 4) * NPIX + g];
    inv[g] = 1.0f / fmaxf(sqrtf(ss), 1e-12f);
}

// ---------------------------------------------------------------- K2b: loss
extern "C" __global__ void __launch_bounds__(NT2)
dcl_loss(const float* __restrict__ part, const float* __restrict__ inv,
         const int* __restrict__ labels, const int* __restrict__ dirs,
         double* __restrict__ acc)
{
    const int g   = blockIdx.x * NT2 + threadIdx.x;
    const int n   = g / HW, pix = g - n * HW;
    const int gi  = pix / W_, gj = pix - gi * W_;

    float s[9];
    #pragma unroll
    for (int d = 0; d < 9; ++d) {
        float v = part[(size_t)d * NPIX + g];
        #pragma unroll
        for (int sl = 1; sl < CSPLIT; ++sl)
            v += part[((size_t)sl * 9 + d) * NPIX + g];
        s[d] = v;
    }

    const float invc = inv[g] * INV_T;
    const int r0 = n * HW + max(gi - 1, 0) * W_;
    const int r1 = n * HW + gi * W_;
    const int r2 = n * HW + min(gi + 1, H_ - 1) * W_;
    const int c0 = max(gj - 1, 0), c1 = gj, c2 = min(gj + 1, W_ - 1);

    const float l00 = s[0] * invc * inv[r0 + c0];
    const float l01 = s[1] * invc * inv[r0 + c1];
    const float l02 = s[2] * invc * inv[r0 + c2];
    const float l10 = s[3] * invc * inv[r1 + c0];
    const float l11 = s[4] * invc * inv[r1 + c1];
    const float l12 = s[5] * invc * inv[r1 + c2];
    const float l20 = s[6] * invc * inv[r2 + c0];
    const float l21 = s[7] * invc * inv[r2 + c1];
    const float l22 = s[8] * invc * inv[r2 + c2];

    float denom = 0.f, sumlog = 0.f;
    #pragma unroll
    for (int m = 0; m < N_; ++m) {
        int d0 = dirs[((m * 2 + 0) * H_ + gi) * W_ + gj];
        int d1 = dirs[((m * 2 + 1) * H_ + gi) * W_ + gj];
        float q0 = sel3(d1, l00, l01, l02);
        float q1 = sel3(d1, l10, l11, l12);
        float q2 = sel3(d1, l20, l21, l22);
        float lm = sel3(d0, q0, q1, q2);
        int labm = labels[m * HW + pix];
        int labn = labels[n * HW + (gi + d0) * W_ + (gj + d1)];
        bool msk = (labm == labn);
        float e = msk ? __expf(lm) : 0.f;
        denom += e;
        sumlog += msk ? lm : -INFINITY;
    }
    float lp = 8.0f * __logf(denom + 1e-6f) - sumlog;

    #pragma unroll
    for (int off = 32; off > 0; off >>= 1) lp += __shfl_down(lp, off, 64);
    __shared__ float red[NT2 / 64];
    const int lane = threadIdx.x & 63, wv = threadIdx.x >> 6;
    if (lane == 0) red[wv] = lp;
    __syncthreads();
    if (threadIdx.x == 0) {
        float t = red[0] + red[1] + red[2] + red[3];
        atomicAdd(acc, (double)t);
    }
}

extern "C" __global__ void dcl_final(const double* __restrict__ acc,
                                     float* __restrict__ out)
{
    out[0] = (float)(acc[0] / TOTAL);
}

// ---------------------------------------------------------------- fallback (R2)
extern "C" __global__ void __launch_bounds__(NT)
dcl_mono(const float* __restrict__ feat,
         const int* __restrict__ labels,
         const int* __restrict__ dirs,
         double* __restrict__ acc)
{
    __shared__ float tiles[2][KCH][TILE_E];
    __shared__ float ssbuf[TILE_E];
    __shared__ float red[8];

    const int tid = threadIdx.x;
    const int n   = blockIdx.y;
    const int gy0 = blockIdx.x * TH;

    int gofs0, gofs1 = 0;
    {
        int r = tid / TWID, col = tid - r * TWID;
        gofs0 = min(max(gy0 + r - 1, 0), H_ - 1) * W_ + min(max(col - 1, 0), W_ - 1);
        if (tid < EXTRA) {
            int t2 = tid + NT;
            r = t2 / TWID; col = t2 - r * TWID;
            gofs1 = min(max(gy0 + r - 1, 0), H_ - 1) * W_ + min(max(col - 1, 0), W_ - 1);
        }
    }
    const int ty = tid / W_, tx = tid - ty * W_;
    const int gi = gy0 + ty, gj = tx;
    const int ci = (ty + 1) * TWID + (tx + 1);
    const float* plane = feat + (size_t)n * C_ * HW;
    float ss0 = 0.f, ss1 = 0.f;

    #pragma unroll
    for (int k = 0; k < KCH; ++k) {
        float v = plane[(size_t)k * HW + gofs0];
        tiles[0][k][tid] = v; ss0 += v * v;
    }
    if (tid < EXTRA) {
        #pragma unroll
        for (int k = 0; k < KCH; ++k) {
            float v = plane[(size_t)k * HW + gofs1];
            tiles[0][k][tid + NT] = v; ss1 += v * v;
        }
    }
    __syncthreads();

    float s00=0.f,s01=0.f,s02=0.f,s10=0.f,s11=0.f,s12=0.f,s20=0.f,s21=0.f,s22=0.f;
    for (int t = 0; t < C_ / KCH; ++t) {
        float pv0[KCH], pv1[KCH];
        const bool more = (t + 1 < C_ / KCH);
        if (more) {
            const float* p = plane + (size_t)(t + 1) * KCH * HW;
            #pragma unroll
            for (int k = 0; k < KCH; ++k) pv0[k] = p[(size_t)k * HW + gofs0];
            if (tid < EXTRA) {
                #pragma unroll
                for (int k = 0; k < KCH; ++k) pv1[k] = p[(size_t)k * HW + gofs1];
            }
        }
        const float* cur = &tiles[t & 1][0][0];
        #pragma unroll
        for (int k = 0; k < KCH; ++k) {
            const float* cp = cur + k * TILE_E;
            float fc = cp[ci];
            s00 += fc * cp[ci - TWID - 1]; s01 += fc * cp[ci - TWID]; s02 += fc * cp[ci - TWID + 1];
            s10 += fc * cp[ci - 1];        s11 += fc * fc;            s12 += fc * cp[ci + 1];
            s20 += fc * cp[ci + TWID - 1]; s21 += fc * cp[ci + TWID]; s22 += fc * cp[ci + TWID + 1];
        }
        if (more) {
            float* nxt = &tiles[(t + 1) & 1][0][0];
            #pragma unroll
            for (int k = 0; k < KCH; ++k) { float v = pv0[k]; nxt[k*TILE_E+tid]=v; ss0+=v*v; }
            if (tid < EXTRA) {
                #pragma unroll
                for (int k = 0; k < KCH; ++k) { float v = pv1[k]; nxt[k*TILE_E+tid+NT]=v; ss1+=v*v; }
            }
        }
        __syncthreads();
    }

    ssbuf[tid] = 1.0f / fmaxf(sqrtf(ss0), 1e-12f);
    if (tid < EXTRA) ssbuf[tid + NT] = 1.0f / fmaxf(sqrtf(ss1), 1e-12f);
    __syncthreads();

    const float invc = ssbuf[ci] * INV_T;
    const float l00 = s00*invc*ssbuf[ci-TWID-1], l01 = s01*invc*ssbuf[ci-TWID], l02 = s02*invc*ssbuf[ci-TWID+1];
    const float l10 = s10*invc*ssbuf[ci-1],      l11 = s11*invc*ssbuf[ci],      l12 = s12*invc*ssbuf[ci+1];
    const float l20 = s20*invc*ssbuf[ci+TWID-1], l21 = s21*invc*ssbuf[ci+TWID], l22 = s22*invc*ssbuf[ci+TWID+1];

    const int pix = gi * W_ + gj;
    float denom = 0.f, sumlog = 0.f;
    #pragma unroll
    for (int m = 0; m < N_; ++m) {
        int d0 = dirs[((m * 2 + 0) * H_ + gi) * W_ + gj];
        int d1 = dirs[((m * 2 + 1) * H_ + gi) * W_ + gj];
        float q0 = sel3(d1, l00, l01, l02);
        float q1 = sel3(d1, l10, l11, l12);
        float q2 = sel3(d1, l20, l21, l22);
        float lm = sel3(d0, q0, q1, q2);
        int labm = labels[m * HW + pix];
        int labn = labels[n * HW + (gi + d0) * W_ + (gj + d1)];
        bool msk = (labm == labn);
        float e = msk ? __expf(lm) : 0.f;
        denom += e; sumlog += msk ? lm : -INFINITY;
    }
    float lp = 8.0f * __logf(denom + 1e-6f) - sumlog;

    #pragma unroll
    for (int off = 32; off > 0; off >>= 1) lp += __shfl_down(lp, off, 64);
    const int wave = tid >> 6, lane = tid & 63;
    if (lane == 0) red[wave] = lp;
    __syncthreads();
    if (tid == 0) {
        float t = 0.f;
        #pragma unroll
        for (int w = 0; w < NT / 64; ++w) t += red[w];
        atomicAdd(acc, (double)t);
    }
}

// ---------------------------------------------------------------- launch
extern "C" void kernel_launch(void* const* d_in, const int* in_sizes, int n_in,
                              void* d_out, int out_size, void* d_ws, size_t ws_size,
                              hipStream_t stream) {
    const float* feat   = (const float*)d_in[0];
    const int*   labels = (const int*)d_in[1];
    const int*   dirs   = (const int*)d_in[2];
    float* out = (float*)d_out;

    if (ws_size >= WS_NEEDED) {
        float*  part = (float*)d_ws;
        float*  inv  = part + PART_FLOATS;
        double* acc  = (double*)(inv + NPIX);
        hipMemsetAsync(acc, 0, sizeof(double), stream);
        dcl_part<<<dim3(H_ / TH, N_, CSPLIT), NT, 0, stream>>>(feat, part);
        dcl_norm<<<NBLK2, NT2, 0, stream>>>(part, inv);
        dcl_loss<<<NBLK2, NT2, 0, stream>>>(part, inv, labels, dirs, acc);
        dcl_final<<<1, 1, 0, stream>>>(acc, out);
    } else {
        double* acc = (double*)d_ws;
        hipMemsetAsync(acc, 0, sizeof(double), stream);
        dcl_mono<<<dim3(H_ / TH, N_), NT, 0, stream>>>(feat, labels, dirs, acc);
        dcl_final<<<1, 1, 0, stream>>>(acc, out);
    }
}

// Round 5
// 136.656 us; speedup vs baseline: 1.8965x; 1.8965x over previous
//
#include <hip/hip_runtime.h>
#include <math.h>

// DirectionalContrastiveLoss — N=8, C=192, H=W=112, T=0.1
//
// R5: fused single kernel (R2 structure — the R4 split-to-global variant
// spilled to scratch and moved 570MB). Two changes vs R2:
//  1) 2-row tiles / 256-thread blocks -> 448 independent blocks (~1.75/CU):
//     two barrier domains per CU so one block's compute hides the other's
//     global-load latency (R2 had 224 blocks, 0.875/CU, latency exposed).
//  2) channels staged as float2 pairs -> ds_read_b64 halves LDS instr count.
// Workspace use: 8 bytes (acc). No partials in global memory.

namespace {
constexpr int N_ = 8, C_ = 192, H_ = 112, W_ = 112;
constexpr int HW = H_ * W_;
constexpr int TH = 2;                 // pixel rows per block
constexpr int TROWS = TH + 2;         // 4 rows incl. halo
constexpr int TWID = W_ + 2;          // 114 cols incl. halo
constexpr int TILE_E = TROWS * TWID;  // 456 slots
constexpr int NT = 256;               // 4 waves
constexpr int NPX = TH * W_;          // 224 compute threads
constexpr int EXTRA = TILE_E - NT;    // 200 threads own a 2nd slot
constexpr int KCH = 4;                // channels per chunk = 2 float2 groups
constexpr int NCHUNK = C_ / KCH;      // 48
constexpr float INV_T = 10.0f;
constexpr double TOTAL = (double)N_ * N_ * H_ * W_;  // 802816
}

__device__ __forceinline__ float sel3(int d, float a, float b, float c) {
    float r = (d < 0) ? a : b;
    return (d > 0) ? c : r;
}

extern "C" __global__ void __launch_bounds__(NT, 2)
dcl_main(const float* __restrict__ feat,
         const int* __restrict__ labels,
         const int* __restrict__ dirs,
         double* __restrict__ acc)
{
    __shared__ float2 tiles[2][2][TILE_E];   // [buf][pair-group][slot] 14.6 KB
    __shared__ float ssbuf[TILE_E];
    __shared__ float red[NT / 64];

    const int tid = threadIdx.x;
    const int n   = blockIdx.y;
    const int gy0 = blockIdx.x * TH;

    // ---- staging slot -> clamped global offset
    int gofs0, gofs1 = 0;
    {
        int r = tid / TWID, col = tid - r * TWID;
        gofs0 = min(max(gy0 + r - 1, 0), H_ - 1) * W_ + min(max(col - 1, 0), W_ - 1);
        if (tid < EXTRA) {
            int t2 = tid + NT;
            r = t2 / TWID; col = t2 - r * TWID;
            gofs1 = min(max(gy0 + r - 1, 0), H_ - 1) * W_ + min(max(col - 1, 0), W_ - 1);
        }
    }

    const bool is_px = (tid < NPX);
    const int ty = tid / W_;              // 0..1 for compute threads
    const int tx = tid - ty * W_;
    const int gi = gy0 + ty;
    const int gj = tx;
    const int ci = (ty + 1) * TWID + (tx + 1);

    const float* __restrict__ plane = feat + (size_t)n * C_ * HW;

    float ss0 = 0.0f, ss1 = 0.0f;

    // ---- prologue: stage chunk 0 into buffer 0 (ss accumulated at stage time)
    {
        float v0 = plane[gofs0], v1 = plane[HW + gofs0];
        float v2 = plane[2 * HW + gofs0], v3 = plane[3 * HW + gofs0];
        ss0 += v0 * v0 + v1 * v1 + v2 * v2 + v3 * v3;
        tiles[0][0][tid] = make_float2(v0, v1);
        tiles[0][1][tid] = make_float2(v2, v3);
        if (tid < EXTRA) {
            float u0 = plane[gofs1], u1 = plane[HW + gofs1];
            float u2 = plane[2 * HW + gofs1], u3 = plane[3 * HW + gofs1];
            ss1 += u0 * u0 + u1 * u1 + u2 * u2 + u3 * u3;
            tiles[0][0][tid + NT] = make_float2(u0, u1);
            tiles[0][1][tid + NT] = make_float2(u2, u3);
        }
    }
    __syncthreads();

    float s[9];
    #pragma unroll
    for (int d = 0; d < 9; ++d) s[d] = 0.0f;

    // ---- chunk loop: 1 barrier per 4 channels, double-buffered
    for (int t = 0; t < NCHUNK; ++t) {
        float pv0[KCH], pv1[KCH];
        const bool more = (t + 1 < NCHUNK);
        if (more) {
            const float* p = plane + (size_t)(t + 1) * KCH * HW;
            #pragma unroll
            for (int k = 0; k < KCH; ++k) pv0[k] = p[(size_t)k * HW + gofs0];
            if (tid < EXTRA) {
                #pragma unroll
                for (int k = 0; k < KCH; ++k) pv1[k] = p[(size_t)k * HW + gofs1];
            }
        }

        if (is_px) {
            #pragma unroll
            for (int g = 0; g < 2; ++g) {
                const float2* __restrict__ cp = tiles[t & 1][g];
                float2 fc  = cp[ci];
                float2 n00 = cp[ci - TWID - 1];
                float2 n01 = cp[ci - TWID];
                float2 n02 = cp[ci - TWID + 1];
                float2 n10 = cp[ci - 1];
                float2 n12 = cp[ci + 1];
                float2 n20 = cp[ci + TWID - 1];
                float2 n21 = cp[ci + TWID];
                float2 n22 = cp[ci + TWID + 1];
                s[0] = fmaf(fc.x, n00.x, s[0]); s[0] = fmaf(fc.y, n00.y, s[0]);
                s[1] = fmaf(fc.x, n01.x, s[1]); s[1] = fmaf(fc.y, n01.y, s[1]);
                s[2] = fmaf(fc.x, n02.x, s[2]); s[2] = fmaf(fc.y, n02.y, s[2]);
                s[3] = fmaf(fc.x, n10.x, s[3]); s[3] = fmaf(fc.y, n10.y, s[3]);
                s[4] = fmaf(fc.x, fc.x,  s[4]); s[4] = fmaf(fc.y, fc.y,  s[4]);
                s[5] = fmaf(fc.x, n12.x, s[5]); s[5] = fmaf(fc.y, n12.y, s[5]);
                s[6] = fmaf(fc.x, n20.x, s[6]); s[6] = fmaf(fc.y, n20.y, s[6]);
                s[7] = fmaf(fc.x, n21.x, s[7]); s[7] = fmaf(fc.y, n21.y, s[7]);
                s[8] = fmaf(fc.x, n22.x, s[8]); s[8] = fmaf(fc.y, n22.y, s[8]);
            }
        }

        if (more) {
            float2* nxt0 = tiles[(t + 1) & 1][0];
            float2* nxt1 = tiles[(t + 1) & 1][1];
            ss0 += pv0[0]*pv0[0] + pv0[1]*pv0[1] + pv0[2]*pv0[2] + pv0[3]*pv0[3];
            nxt0[tid] = make_float2(pv0[0], pv0[1]);
            nxt1[tid] = make_float2(pv0[2], pv0[3]);
            if (tid < EXTRA) {
                ss1 += pv1[0]*pv1[0] + pv1[1]*pv1[1] + pv1[2]*pv1[2] + pv1[3]*pv1[3];
                nxt0[tid + NT] = make_float2(pv1[0], pv1[1]);
                nxt1[tid + NT] = make_float2(pv1[2], pv1[3]);
            }
            __syncthreads();
        }
    }

    // ---- publish inverse norms (slot owners)
    __syncthreads();   // ensure last chunk's ds_reads done before reuse? (ssbuf separate; this orders ss publication)
    ssbuf[tid] = 1.0f / fmaxf(sqrtf(ss0), 1e-12f);
    if (tid < EXTRA)
        ssbuf[tid + NT] = 1.0f / fmaxf(sqrtf(ss1), 1e-12f);
    __syncthreads();

    float lp = 0.0f;
    if (is_px) {
        const float invc = ssbuf[ci] * INV_T;
        const float l00 = s[0] * invc * ssbuf[ci - TWID - 1];
        const float l01 = s[1] * invc * ssbuf[ci - TWID];
        const float l02 = s[2] * invc * ssbuf[ci - TWID + 1];
        const float l10 = s[3] * invc * ssbuf[ci - 1];
        const float l11 = s[4] * invc * ssbuf[ci];
        const float l12 = s[5] * invc * ssbuf[ci + 1];
        const float l20 = s[6] * invc * ssbuf[ci + TWID - 1];
        const float l21 = s[7] * invc * ssbuf[ci + TWID];
        const float l22 = s[8] * invc * ssbuf[ci + TWID + 1];

        const int pix = gi * W_ + gj;
        float denom = 0.f, sumlog = 0.f;
        #pragma unroll
        for (int m = 0; m < N_; ++m) {
            int d0 = dirs[((m * 2 + 0) * H_ + gi) * W_ + gj];
            int d1 = dirs[((m * 2 + 1) * H_ + gi) * W_ + gj];
            float q0 = sel3(d1, l00, l01, l02);
            float q1 = sel3(d1, l10, l11, l12);
            float q2 = sel3(d1, l20, l21, l22);
            float lm = sel3(d0, q0, q1, q2);
            int labm = labels[m * HW + pix];
            int labn = labels[n * HW + (gi + d0) * W_ + (gj + d1)];
            bool msk = (labm == labn);
            float e = msk ? __expf(lm) : 0.f;
            denom += e;
            sumlog += msk ? lm : -INFINITY;
        }
        lp = 8.0f * __logf(denom + 1e-6f) - sumlog;
    }

    // ---- block reduction (4 waves)
    #pragma unroll
    for (int off = 32; off > 0; off >>= 1) lp += __shfl_down(lp, off, 64);
    const int wave = tid >> 6, lane = tid & 63;
    if (lane == 0) red[wave] = lp;
    __syncthreads();
    if (tid == 0) {
        float t = red[0] + red[1] + red[2] + red[3];
        atomicAdd(acc, (double)t);
    }
}

extern "C" __global__ void dcl_final(const double* __restrict__ acc,
                                     float* __restrict__ out)
{
    out[0] = (float)(acc[0] / TOTAL);
}

extern "C" void kernel_launch(void* const* d_in, const int* in_sizes, int n_in,
                              void* d_out, int out_size, void* d_ws, size_t ws_size,
                              hipStream_t stream) {
    const float* feat   = (const float*)d_in[0];
    const int*   labels = (const int*)d_in[1];
    const int*   dirs   = (const int*)d_in[2];
    double* acc = (double*)d_ws;
    float*  out = (float*)d_out;

    hipMemsetAsync(acc, 0, sizeof(double), stream);
    dim3 grid(H_ / TH, N_);               // (56, 8) = 448 blocks
    dcl_main<<<grid, NT, 0, stream>>>(feat, labels, dirs, acc);
    dcl_final<<<1, 1, 0, stream>>>(acc, out);
}

// Round 6
// 126.958 us; speedup vs baseline: 2.0414x; 1.0764x over previous
//
#include <hip/hip_runtime.h>
#include <math.h>

// DirectionalContrastiveLoss — N=8, C=192, H=W=112, T=0.1
//
// R6: R5's fused algorithm, reshaped for latency overlap.
//  - NT=128 (2-wave barrier domains), tile = 2 rows x 56 cols (+halo = 4x58)
//    -> 896 blocks = 3.5 independent domains/CU, 7 waves/CU (R5: 1.75 domains).
//    Occupancy was grid-limited (VGPR 36 / LDS 17KB allow ~8 blocks/CU).
//  - KCH=8 channels per barrier (24 barriers; ~800cyc compute/chunk covers
//    the ~900cyc load latency in-block; cross-block overlap covers the rest).
//  - per-block partials in d_ws (no memset dispatch, no global atomic).

namespace {
constexpr int N_ = 8, C_ = 192, H_ = 112, W_ = 112;
constexpr int HW = H_ * W_;
constexpr int TH = 2;                  // pixel rows per block
constexpr int WS = 56;                 // pixel cols per block
constexpr int TROWS = TH + 2;          // 4
constexpr int TCOLS = WS + 2;          // 58
constexpr int TILE_E = TROWS * TCOLS;  // 232
constexpr int NT = 128;                // 2 waves
constexpr int NPX = TH * WS;           // 112 compute threads
constexpr int EXTRA = TILE_E - NT;     // 104 threads own a 2nd slot
constexpr int KCH = 8;                 // channels per chunk
constexpr int GRP = KCH / 2;           // 4 float2 groups
constexpr int NCHUNK = C_ / KCH;       // 24
constexpr int NBLK = 2 * (H_ / TH) * N_;  // 896
constexpr float INV_T = 10.0f;
constexpr double TOTAL = (double)N_ * N_ * H_ * W_;  // 802816
}

__device__ __forceinline__ float sel3(int d, float a, float b, float c) {
    float r = (d < 0) ? a : b;
    return (d > 0) ? c : r;
}

extern "C" __global__ void __launch_bounds__(NT, 4)
dcl_main(const float* __restrict__ feat,
         const int* __restrict__ labels,
         const int* __restrict__ dirs,
         double* __restrict__ partial, int use_partial)
{
    __shared__ float2 tiles[2][GRP][TILE_E];   // 14.8 KB
    __shared__ float ssbuf[TILE_E];
    __shared__ float red[NT / 64];

    const int tid = threadIdx.x;
    const int gx0 = blockIdx.x * WS;
    const int gy0 = blockIdx.y * TH;
    const int n   = blockIdx.z;

    // ---- staging slot -> clamped global offset
    int gofs0, gofs1 = 0;
    {
        int r = tid / TCOLS, c = tid - r * TCOLS;
        gofs0 = min(max(gy0 + r - 1, 0), H_ - 1) * W_ + min(max(gx0 + c - 1, 0), W_ - 1);
        if (tid < EXTRA) {
            int t2 = tid + NT;
            r = t2 / TCOLS; c = t2 - r * TCOLS;
            gofs1 = min(max(gy0 + r - 1, 0), H_ - 1) * W_ + min(max(gx0 + c - 1, 0), W_ - 1);
        }
    }

    const bool is_px = (tid < NPX);
    const int ty = tid / WS;               // 0..1
    const int tx = tid - ty * WS;          // 0..55
    const int gi = gy0 + ty;
    const int gj = gx0 + tx;
    const int ci = (ty + 1) * TCOLS + (tx + 1);

    const float* __restrict__ plane = feat + (size_t)n * C_ * HW;

    float ss0 = 0.0f, ss1 = 0.0f;

    // ---- prologue: stage chunk 0 into buffer 0
    {
        #pragma unroll
        for (int g = 0; g < GRP; ++g) {
            float v0 = plane[(size_t)(2 * g) * HW + gofs0];
            float v1 = plane[(size_t)(2 * g + 1) * HW + gofs0];
            ss0 += v0 * v0 + v1 * v1;
            tiles[0][g][tid] = make_float2(v0, v1);
        }
        if (tid < EXTRA) {
            #pragma unroll
            for (int g = 0; g < GRP; ++g) {
                float u0 = plane[(size_t)(2 * g) * HW + gofs1];
                float u1 = plane[(size_t)(2 * g + 1) * HW + gofs1];
                ss1 += u0 * u0 + u1 * u1;
                tiles[0][g][tid + NT] = make_float2(u0, u1);
            }
        }
    }
    __syncthreads();

    float s[9];
    #pragma unroll
    for (int d = 0; d < 9; ++d) s[d] = 0.0f;

    // ---- chunk loop: 1 barrier per 8 channels, double-buffered
    for (int t = 0; t < NCHUNK; ++t) {
        float pv0[KCH], pv1[KCH];
        const bool more = (t + 1 < NCHUNK);
        if (more) {
            const float* p = plane + (size_t)(t + 1) * KCH * HW;
            #pragma unroll
            for (int k = 0; k < KCH; ++k) pv0[k] = p[(size_t)k * HW + gofs0];
            if (tid < EXTRA) {
                #pragma unroll
                for (int k = 0; k < KCH; ++k) pv1[k] = p[(size_t)k * HW + gofs1];
            }
        }

        if (is_px) {
            #pragma unroll
            for (int g = 0; g < GRP; ++g) {
                const float2* __restrict__ cp = tiles[t & 1][g];
                float2 fc  = cp[ci];
                float2 n00 = cp[ci - TCOLS - 1];
                float2 n01 = cp[ci - TCOLS];
                float2 n02 = cp[ci - TCOLS + 1];
                float2 n10 = cp[ci - 1];
                float2 n12 = cp[ci + 1];
                float2 n20 = cp[ci + TCOLS - 1];
                float2 n21 = cp[ci + TCOLS];
                float2 n22 = cp[ci + TCOLS + 1];
                s[0] = fmaf(fc.x, n00.x, s[0]); s[0] = fmaf(fc.y, n00.y, s[0]);
                s[1] = fmaf(fc.x, n01.x, s[1]); s[1] = fmaf(fc.y, n01.y, s[1]);
                s[2] = fmaf(fc.x, n02.x, s[2]); s[2] = fmaf(fc.y, n02.y, s[2]);
                s[3] = fmaf(fc.x, n10.x, s[3]); s[3] = fmaf(fc.y, n10.y, s[3]);
                s[4] = fmaf(fc.x, fc.x,  s[4]); s[4] = fmaf(fc.y, fc.y,  s[4]);
                s[5] = fmaf(fc.x, n12.x, s[5]); s[5] = fmaf(fc.y, n12.y, s[5]);
                s[6] = fmaf(fc.x, n20.x, s[6]); s[6] = fmaf(fc.y, n20.y, s[6]);
                s[7] = fmaf(fc.x, n21.x, s[7]); s[7] = fmaf(fc.y, n21.y, s[7]);
                s[8] = fmaf(fc.x, n22.x, s[8]); s[8] = fmaf(fc.y, n22.y, s[8]);
            }
        }

        if (more) {
            #pragma unroll
            for (int g = 0; g < GRP; ++g) {
                float v0 = pv0[2 * g], v1 = pv0[2 * g + 1];
                ss0 += v0 * v0 + v1 * v1;
                tiles[(t + 1) & 1][g][tid] = make_float2(v0, v1);
            }
            if (tid < EXTRA) {
                #pragma unroll
                for (int g = 0; g < GRP; ++g) {
                    float u0 = pv1[2 * g], u1 = pv1[2 * g + 1];
                    ss1 += u0 * u0 + u1 * u1;
                    tiles[(t + 1) & 1][g][tid + NT] = make_float2(u0, u1);
                }
            }
            __syncthreads();
        }
    }

    // ---- publish inverse norms (slot owners)
    __syncthreads();
    ssbuf[tid] = 1.0f / fmaxf(sqrtf(ss0), 1e-12f);
    if (tid < EXTRA)
        ssbuf[tid + NT] = 1.0f / fmaxf(sqrtf(ss1), 1e-12f);
    __syncthreads();

    float lp = 0.0f;
    if (is_px) {
        const float invc = ssbuf[ci] * INV_T;
        const float l00 = s[0] * invc * ssbuf[ci - TCOLS - 1];
        const float l01 = s[1] * invc * ssbuf[ci - TCOLS];
        const float l02 = s[2] * invc * ssbuf[ci - TCOLS + 1];
        const float l10 = s[3] * invc * ssbuf[ci - 1];
        const float l11 = s[4] * invc * ssbuf[ci];
        const float l12 = s[5] * invc * ssbuf[ci + 1];
        const float l20 = s[6] * invc * ssbuf[ci + TCOLS - 1];
        const float l21 = s[7] * invc * ssbuf[ci + TCOLS];
        const float l22 = s[8] * invc * ssbuf[ci + TCOLS + 1];

        const int pix = gi * W_ + gj;
        float denom = 0.f, sumlog = 0.f;
        #pragma unroll
        for (int m = 0; m < N_; ++m) {
            int d0 = dirs[((m * 2 + 0) * H_ + gi) * W_ + gj];
            int d1 = dirs[((m * 2 + 1) * H_ + gi) * W_ + gj];
            float q0 = sel3(d1, l00, l01, l02);
            float q1 = sel3(d1, l10, l11, l12);
            float q2 = sel3(d1, l20, l21, l22);
            float lm = sel3(d0, q0, q1, q2);
            int labm = labels[m * HW + pix];
            int labn = labels[n * HW + (gi + d0) * W_ + (gj + d1)];
            bool msk = (labm == labn);
            float e = msk ? __expf(lm) : 0.f;
            denom += e;
            sumlog += msk ? lm : -INFINITY;
        }
        lp = 8.0f * __logf(denom + 1e-6f) - sumlog;
    }

    // ---- block reduction (2 waves)
    #pragma unroll
    for (int off = 32; off > 0; off >>= 1) lp += __shfl_down(lp, off, 64);
    const int wave = tid >> 6, lane = tid & 63;
    if (lane == 0) red[wave] = lp;
    __syncthreads();
    if (tid == 0) {
        const int bid = (blockIdx.z * gridDim.y + blockIdx.y) * gridDim.x + blockIdx.x;
        float t = red[0] + red[1];
        if (use_partial) partial[bid] = (double)t;
        else atomicAdd(partial, (double)t);
    }
}

extern "C" __global__ void __launch_bounds__(256)
dcl_final(const double* __restrict__ partial, float* __restrict__ out, int nblk)
{
    const int tid = threadIdx.x;
    double s = 0.0;
    for (int i = tid; i < nblk; i += 256) s += partial[i];
    #pragma unroll
    for (int off = 32; off > 0; off >>= 1) s += __shfl_down(s, off, 64);
    __shared__ double red[4];
    const int lane = tid & 63, wv = tid >> 6;
    if (lane == 0) red[wv] = s;
    __syncthreads();
    if (tid == 0) out[0] = (float)((red[0] + red[1] + red[2] + red[3]) / TOTAL);
}

extern "C" void kernel_launch(void* const* d_in, const int* in_sizes, int n_in,
                              void* d_out, int out_size, void* d_ws, size_t ws_size,
                              hipStream_t stream) {
    const float* feat   = (const float*)d_in[0];
    const int*   labels = (const int*)d_in[1];
    const int*   dirs   = (const int*)d_in[2];
    double* acc = (double*)d_ws;
    float*  out = (float*)d_out;

    const int use_partial = (ws_size >= (size_t)NBLK * sizeof(double)) ? 1 : 0;
    if (!use_partial) hipMemsetAsync(acc, 0, sizeof(double), stream);
    dim3 grid(2, H_ / TH, N_);            // (2, 56, 8) = 896 blocks
    dcl_main<<<grid, NT, 0, stream>>>(feat, labels, dirs, acc, use_partial);
    dcl_final<<<1, 256, 0, stream>>>(acc, out, use_partial ? NBLK : 1);
}